// Round 4
// baseline (51.589 us; speedup 1.0000x reference)
//
#include <hip/hip_runtime.h>

typedef __attribute__((ext_vector_type(4))) float f32x4;
typedef __attribute__((ext_vector_type(8))) __bf16 bf16x8;
typedef __attribute__((ext_vector_type(8))) unsigned short ushort8v;

#define NGRP   100
#define DDIM   768
#define FDIM   100
#define NCLS   10000
#define NSTEP  12                       // 768 / 64
#define NTILE  7                        // ceil(112/16) f-tiles
#define NCHUNK 14                       // chunks actually consumed (7 tiles x 2 k-halves)
#define NCHUNK_PAD 16                   // chunks DMA'd (uniform 4 per wave)
#define CH_SHORTS 512                   // one chunk: 64 lanes x 8 bf16 (16 B/lane)
#define STEP_SHORTS (NCHUNK_PAD * CH_SHORTS)   // 8192 shorts = 16 KB per k-step
#define G_SHORTS (NSTEP * STEP_SHORTS)         // 98304 shorts per group

#define GLOBAL_AS __attribute__((address_space(1)))
#define LDS_AS    __attribute__((address_space(3)))

static __device__ __forceinline__ unsigned short f2bf(float f) {
    __bf16 b = (__bf16)f;   // RNE; pairs into v_cvt_pk_bf16_f32
    return __builtin_bit_cast(unsigned short, b);
}

// ---- pre-pass: W (g,d,f) f32 -> Wt fragment-linear bf16 ----
// Wt[g][step][c][lane][j] = W[g][step*64 + (c&1)*32 + (lane>>4)*8 + j][min((c>>1)*16 + (lane&15), 99)]
// chunks 14,15 of each step are padding (DMA'd, never read by MFMA, never written here).
__global__ __launch_bounds__(256) void build_wt(
    const float* __restrict__ W, unsigned short* __restrict__ Wt)
{
    __shared__ unsigned short lt[FDIM * 66];   // [f][d-offset], 33-dword stride: conflict-free
    const int b = blockIdx.x, g = b / 12, step = b % 12;
    const int tid = threadIdx.x;

    const float* Wg = W + (size_t)g * (DDIM * FDIM) + (size_t)step * 64 * FDIM;
#pragma unroll
    for (int j = 0; j < 25; ++j) {          // 64 d-rows x 100 f, coalesced reads
        const int i = tid + j * 256;
        const int r = i / 100, f = i % 100;
        lt[f * 66 + r] = f2bf(Wg[i]);
    }
    __syncthreads();

    unsigned short* out = Wt + (size_t)g * G_SHORTS + step * STEP_SHORTS;
#pragma unroll
    for (int j = 0; j < 4; ++j) {
        const int idx = tid + j * 256;      // 0..895 fragment-lane slots
        if (idx < NCHUNK * 64) {
            const int c = idx >> 6, lane = idx & 63;
            const int t = c >> 1, half = c & 1;
            int f = t * 16 + (lane & 15); if (f > FDIM - 1) f = FDIM - 1;
            const int kk = half * 32 + (lane >> 4) * 8;
            const unsigned short* src = &lt[f * 66 + kk];
            ushort8v v;
            v[0]=src[0]; v[1]=src[1]; v[2]=src[2]; v[3]=src[3];
            v[4]=src[4]; v[5]=src[5]; v[6]=src[6]; v[7]=src[7];
            *(ushort8v*)(out + (size_t)idx * 8) = v;    // coalesced 16B stores
        }
    }
}

// ---- main: triple-buffered DMA, counted vmcnt + raw barrier (T3/T4), A reg-prefetch ----
__global__ __launch_bounds__(256, 3) void gfcp_main(
    const float* __restrict__ H, const unsigned short* __restrict__ Wt,
    const float* __restrict__ Bv, float* __restrict__ Out)
{
    __shared__ unsigned short Bl[3][STEP_SHORTS];   // 3 x 16 KB = 48 KB -> 3 blocks/CU

    // XCD-bijective swizzle (800 % 8 == 0): a group's 8 row-blocks share one XCD L2
    const int bid  = blockIdx.x;
    const int wgid = (bid & 7) * 100 + (bid >> 3);
    const int g    = wgid >> 3;
    const int m0   = (wgid & 7) * 64;

    const int tid  = threadIdx.x;
    const int lane = tid & 63;
    const int wv   = tid >> 6;
    const int r16  = lane & 15;
    const int kg   = lane >> 4;

    const float* Ap = H + (size_t)(m0 + wv * 16 + r16) * (NGRP * DDIM)
                        + (size_t)g * DDIM + kg * 8;
    const unsigned short* Bg = Wt + (size_t)g * G_SHORTS + lane * 8;  // per-lane DMA src

    f32x4 acc[NTILE];
#pragma unroll
    for (int t = 0; t < NTILE; ++t) acc[t] = (f32x4)(0.0f);

    f32x4 a[2][4];   // A prefetch, 2 slots x 16 f32

    auto stage = [&](int buf, int step) {   // exactly 4 DMA per wave (uniform vmcnt)
        const unsigned short* gsrc = Bg + step * STEP_SHORTS;
#pragma unroll
        for (int i = 0; i < 4; ++i) {
            const int c = wv * 4 + i;       // wave-uniform chunk id, 0..15
            __builtin_amdgcn_global_load_lds(
                (const GLOBAL_AS void*)(gsrc + c * CH_SHORTS),
                (LDS_AS void*)(&Bl[buf][c * CH_SHORTS]),
                16, 0, 0);
        }
    };
    auto loadA = [&](int slot, int step) {  // exactly 4 global_load_dwordx4
        const float* p = Ap + step * 64;
        a[slot][0] = *(const f32x4*)(p);
        a[slot][1] = *(const f32x4*)(p + 4);
        a[slot][2] = *(const f32x4*)(p + 32);
        a[slot][3] = *(const f32x4*)(p + 36);
    };
    auto compute = [&](int buf, int slot) {
        const unsigned short* bl = &Bl[buf][0];
#pragma unroll
        for (int s = 0; s < 2; ++s) {
            const f32x4 x = a[slot][2 * s], y = a[slot][2 * s + 1];
            ushort8v u;
            u[0]=f2bf(x[0]); u[1]=f2bf(x[1]); u[2]=f2bf(x[2]); u[3]=f2bf(x[3]);
            u[4]=f2bf(y[0]); u[5]=f2bf(y[1]); u[6]=f2bf(y[2]); u[7]=f2bf(y[3]);
            const bf16x8 af = __builtin_bit_cast(bf16x8, u);
#pragma unroll
            for (int t = 0; t < NTILE; ++t) {
                const ushort8v bu = *(const ushort8v*)(bl + (t * 2 + s) * CH_SHORTS + lane * 8);
                acc[t] = __builtin_amdgcn_mfma_f32_16x16x32_bf16(
                    af, __builtin_bit_cast(bf16x8, bu), acc[t], 0, 0, 0);
            }
        }
    };

    // ---- prologue: A(0),A(1) then S(0),S(1); wait S(0) only (4 newer = S(1)) ----
    loadA(0, 0);
    loadA(1, 1);
    __builtin_amdgcn_sched_barrier(0);      // pin A-loads before DMAs (vmcnt accounting)
    stage(0, 0);
    stage(1, 1);
    asm volatile("s_waitcnt vmcnt(4)" ::: "memory");
    __builtin_amdgcn_s_barrier();

    // ---- main loop: never drain vmcnt to 0 in steady state ----
#pragma unroll
    for (int t = 0; t < NSTEP; ++t) {
        compute(t % 3, t & 1);              // ds_read + MFMA on current buffer
        if (t + 2 < NSTEP) {
            loadA(t & 1, t + 2);            // refill freed A slot (distance 2)
            __builtin_amdgcn_sched_barrier(0);  // A-loads stay before DMAs
            stage((t + 2) % 3, t + 2);      // issue next-next B
        }
        if (t + 1 < NSTEP) {
            // ensure stage(t+1) complete: ops issued after it = loadA(t+2)+stage(t+2)
            if (t + 2 < NSTEP) asm volatile("s_waitcnt vmcnt(8)" ::: "memory");
            else               asm volatile("s_waitcnt vmcnt(0)" ::: "memory");
            __builtin_amdgcn_s_barrier();
        }
    }

    // ---- epilogue: C/D layout col=lane&15, row=(lane>>4)*4+r ----
    const int orow  = m0 + wv * 16 + kg * 4;
    const int fbase = g * FDIM;
#pragma unroll
    for (int t = 0; t < NTILE; ++t) {
        const int fc = t * 16 + r16;
        if (fc < FDIM) {
            const float bv = Bv[fbase + fc];
#pragma unroll
            for (int r = 0; r < 4; ++r) {
                Out[(size_t)(orow + r) * NCLS + fbase + fc] = acc[t][r] + bv;
            }
        }
    }
}

extern "C" void kernel_launch(void* const* d_in, const int* in_sizes, int n_in,
                              void* d_out, int out_size, void* d_ws, size_t ws_size,
                              hipStream_t stream) {
    const float* H  = (const float*)d_in[0];   // (512, 100, 768) f32
    const float* W  = (const float*)d_in[1];   // (100, 768, 100) f32
    const float* Bv = (const float*)d_in[2];   // (10000,) f32
    float* Out = (float*)d_out;                // (512, 10000) f32
    unsigned short* Wt = (unsigned short*)d_ws; // fragment-linear bf16, 19.7 MB padded

    build_wt<<<dim3(1200), dim3(256), 0, stream>>>(W, Wt);
    gfcp_main<<<dim3(800), dim3(256), 0, stream>>>(H, Wt, Bv, Out);
}

// Round 5
// 50.290 us; speedup vs baseline: 1.0258x; 1.0258x over previous
//
#include <hip/hip_runtime.h>

typedef __attribute__((ext_vector_type(4))) float f32x4;
typedef __attribute__((ext_vector_type(8))) __bf16 bf16x8;
typedef __attribute__((ext_vector_type(8))) unsigned short ushort8v;

#define NGRP   100
#define DDIM   768
#define FDIM   100
#define NCLS   10000
#define NSTEP  12                       // 768 / 64
#define NTILE  7                        // ceil(112/16) f-tiles
#define NCHUNK 14                       // 7 f-tiles x 2 k-halves (no pad; 7 per wave)
#define CH_SHORTS 512                   // one chunk: 64 lanes x 8 bf16 (16 B/lane)
#define STEP_SHORTS (NCHUNK * CH_SHORTS)   // 7168 shorts = 14336 B per k-step
#define G_SHORTS (NSTEP * STEP_SHORTS)     // 86016 shorts per group (168 KB)

#define GLOBAL_AS __attribute__((address_space(1)))
#define LDS_AS    __attribute__((address_space(3)))

static __device__ __forceinline__ unsigned short f2bf(float f) {
    __bf16 b = (__bf16)f;   // RNE; pairs into v_cvt_pk_bf16_f32
    return __builtin_bit_cast(unsigned short, b);
}

// ---- pre-pass: W (g,d,f) f32 -> Wt fragment-linear bf16 ----
// Wt[g][step][c][lane][j] = W[g][step*64 + (c&1)*32 + (lane>>4)*8 + j][min((c>>1)*16 + (lane&15), 99)]
__global__ __launch_bounds__(256) void build_wt(
    const float* __restrict__ W, unsigned short* __restrict__ Wt)
{
    __shared__ unsigned short lt[FDIM * 66];   // [f][d-offset], 33-dword stride: conflict-free
    const int b = blockIdx.x, g = b / 12, step = b % 12;
    const int tid = threadIdx.x;

    const float* Wg = W + (size_t)g * (DDIM * FDIM) + (size_t)step * 64 * FDIM;
#pragma unroll
    for (int j = 0; j < 25; ++j) {          // 64 d-rows x 100 f, coalesced reads
        const int i = tid + j * 256;
        const int r = i / 100, f = i % 100;
        lt[f * 66 + r] = f2bf(Wg[i]);
    }
    __syncthreads();

    unsigned short* out = Wt + (size_t)g * G_SHORTS + step * STEP_SHORTS;
#pragma unroll
    for (int j = 0; j < 4; ++j) {
        const int idx = tid + j * 256;      // 0..895 fragment-lane slots
        if (idx < NCHUNK * 64) {
            const int c = idx >> 6, lane = idx & 63;
            const int t = c >> 1, half = c & 1;
            int f = t * 16 + (lane & 15); if (f > FDIM - 1) f = FDIM - 1;
            const int kk = half * 32 + (lane >> 4) * 8;
            const unsigned short* src = &lt[f * 66 + kk];
            ushort8v v;
            v[0]=src[0]; v[1]=src[1]; v[2]=src[2]; v[3]=src[3];
            v[4]=src[4]; v[5]=src[5]; v[6]=src[6]; v[7]=src[7];
            *(ushort8v*)(out + (size_t)idx * 8) = v;    // coalesced 16B stores
        }
    }
}

// ---- main: 128 thr / 2 waves / 2 M-tiles per wave; dbuf DMA; counted vmcnt ----
__global__ __launch_bounds__(128, 3) void gfcp_main(
    const float* __restrict__ H, const unsigned short* __restrict__ Wt,
    const float* __restrict__ Bv, float* __restrict__ Out)
{
    __shared__ unsigned short Bl[2][STEP_SHORTS];   // 2 x 14 KB = 28 KB -> 5 blocks/CU

    // XCD-bijective swizzle (800 % 8 == 0): a group's 8 row-blocks share one XCD L2
    const int bid  = blockIdx.x;
    const int wgid = (bid & 7) * 100 + (bid >> 3);
    const int g    = wgid >> 3;
    const int m0   = (wgid & 7) * 64;

    const int tid  = threadIdx.x;
    const int lane = tid & 63;
    const int wv   = tid >> 6;            // 0..1
    const int r16  = lane & 15;
    const int kg   = lane >> 4;

    const float* Ap0 = H + (size_t)(m0 + wv * 32 + r16) * (NGRP * DDIM)
                         + (size_t)g * DDIM + kg * 8;
    const float* Ap1 = Ap0 + (size_t)16 * (NGRP * DDIM);
    const unsigned short* Bg = Wt + (size_t)g * G_SHORTS + lane * 8;

    f32x4 acc[2][NTILE];
#pragma unroll
    for (int at = 0; at < 2; ++at)
#pragma unroll
        for (int t = 0; t < NTILE; ++t) acc[at][t] = (f32x4)(0.0f);

    f32x4 a[2][2][4];   // [slot][A-tile][4x f32x4]

    auto stage = [&](int buf, int step) {   // exactly 7 DMA per wave
        const unsigned short* gsrc = Bg + step * STEP_SHORTS;
#pragma unroll
        for (int i = 0; i < 7; ++i) {
            const int c = wv * 7 + i;       // wave-uniform chunk id, 0..13
            __builtin_amdgcn_global_load_lds(
                (const GLOBAL_AS void*)(gsrc + c * CH_SHORTS),
                (LDS_AS void*)(&Bl[buf][c * CH_SHORTS]),
                16, 0, 0);
        }
    };
    auto loadA = [&](int slot, int step) {  // exactly 8 global_load_dwordx4
        const float* p0 = Ap0 + step * 64;
        a[slot][0][0] = *(const f32x4*)(p0);
        a[slot][0][1] = *(const f32x4*)(p0 + 4);
        a[slot][0][2] = *(const f32x4*)(p0 + 32);
        a[slot][0][3] = *(const f32x4*)(p0 + 36);
        const float* p1 = Ap1 + step * 64;
        a[slot][1][0] = *(const f32x4*)(p1);
        a[slot][1][1] = *(const f32x4*)(p1 + 4);
        a[slot][1][2] = *(const f32x4*)(p1 + 32);
        a[slot][1][3] = *(const f32x4*)(p1 + 36);
    };
    auto compute = [&](int buf, int slot) { // 14 ds_read_b128 -> 28 MFMA
        const unsigned short* bl = &Bl[buf][0];
#pragma unroll
        for (int s = 0; s < 2; ++s) {
            ushort8v u0, u1;
#pragma unroll
            for (int j = 0; j < 4; ++j) {
                u0[j]   = f2bf(a[slot][0][2*s][j]); u0[j+4] = f2bf(a[slot][0][2*s+1][j]);
                u1[j]   = f2bf(a[slot][1][2*s][j]); u1[j+4] = f2bf(a[slot][1][2*s+1][j]);
            }
            const bf16x8 af0 = __builtin_bit_cast(bf16x8, u0);
            const bf16x8 af1 = __builtin_bit_cast(bf16x8, u1);
#pragma unroll
            for (int t = 0; t < NTILE; ++t) {
                const ushort8v bu = *(const ushort8v*)(bl + (t * 2 + s) * CH_SHORTS + lane * 8);
                const bf16x8 bf = __builtin_bit_cast(bf16x8, bu);
                acc[0][t] = __builtin_amdgcn_mfma_f32_16x16x32_bf16(af0, bf, acc[0][t], 0, 0, 0);
                acc[1][t] = __builtin_amdgcn_mfma_f32_16x16x32_bf16(af1, bf, acc[1][t], 0, 0, 0);
            }
        }
    };

    // ---- prologue: A(0)[8], S(0)[7], A(1)[8]; wait A(0)+S(0) -> vmcnt(8) ----
    loadA(0, 0);
    __builtin_amdgcn_sched_barrier(0);
    stage(0, 0);
    __builtin_amdgcn_sched_barrier(0);
    loadA(1, 1);
    __builtin_amdgcn_sched_barrier(0);
    asm volatile("s_waitcnt vmcnt(8)" ::: "memory");
    __builtin_amdgcn_s_barrier();
    __builtin_amdgcn_sched_barrier(0);

    // ---- main loop (fully unrolled): never drain vmcnt in steady state ----
#pragma unroll
    for (int t = 0; t < NSTEP; ++t) {
        const int cur = t & 1;
        if (t + 1 < NSTEP) {
            stage(cur ^ 1, t + 1);          // issue next-step DMA into free buffer
            __builtin_amdgcn_sched_barrier(0);
        }
        compute(cur, cur);                  // ds_read + MFMA on current buffer
        if (t + 2 < NSTEP) loadA(cur, t + 2);   // refill freed A slot (distance 2)
        if (t + 1 < NSTEP) {
            __builtin_amdgcn_sched_barrier(0);
            // S(t+1) complete: ops newer than it = loadA(t+2) (8) if issued
            if (t + 2 < NSTEP) asm volatile("s_waitcnt vmcnt(8)" ::: "memory");
            else               asm volatile("s_waitcnt vmcnt(0)" ::: "memory");
            __builtin_amdgcn_s_barrier();
            __builtin_amdgcn_sched_barrier(0);  // ds_reads stay behind barrier
        }
    }

    // ---- epilogue: C/D layout col=lane&15, row=(lane>>4)*4+r ----
    const int fbase = g * FDIM;
#pragma unroll
    for (int at = 0; at < 2; ++at) {
        const int orow = m0 + wv * 32 + at * 16 + kg * 4;
#pragma unroll
        for (int t = 0; t < NTILE; ++t) {
            const int fc = t * 16 + r16;
            if (fc < FDIM) {
                const float bv = Bv[fbase + fc];
#pragma unroll
                for (int r = 0; r < 4; ++r) {
                    Out[(size_t)(orow + r) * NCLS + fbase + fc] = acc[at][t][r] + bv;
                }
            }
        }
    }
}

extern "C" void kernel_launch(void* const* d_in, const int* in_sizes, int n_in,
                              void* d_out, int out_size, void* d_ws, size_t ws_size,
                              hipStream_t stream) {
    const float* H  = (const float*)d_in[0];   // (512, 100, 768) f32
    const float* W  = (const float*)d_in[1];   // (100, 768, 100) f32
    const float* Bv = (const float*)d_in[2];   // (10000,) f32
    float* Out = (float*)d_out;                // (512, 10000) f32
    unsigned short* Wt = (unsigned short*)d_ws; // fragment-linear bf16, 17.2 MB

    build_wt<<<dim3(1200), dim3(256), 0, stream>>>(W, Wt);
    gfcp_main<<<dim3(800), dim3(128), 0, stream>>>(H, Wt, Bv, Out);
}